// Round 2
// baseline (250.375 us; speedup 1.0000x reference)
//
#include <hip/hip_runtime.h>

#define N_NODES 50000
#define N_EDGES 100000
#define NUM_RELS 200
#define DIM 64
#define CAP 512            // max nodes per rel bucket (mean ~216, >19 sigma margin)
#define NB 32              // nodes per tile/block
#define TILES_PER_REL (CAP / NB)   // 16

// ---- workspace layout (int32 elements) ----
// last    : [0, 50000)
// cursor  : [50000, 50200)
// bucket_n: [50200, 50200 + 200*512)            node id
// bucket_s: [50200 + 102400, 50200 + 204800)    src node of last edge
#define OFF_LAST   0
#define OFF_CUR    50000
#define OFF_BN     50200
#define OFF_BS     (50200 + NUM_RELS * CAP)

// Kernel 1: init last=-1 and cursor=0
__global__ void init_kernel(int* __restrict__ ws) {
    int i = blockIdx.x * blockDim.x + threadIdx.x;
    if (i < N_NODES) ws[OFF_LAST + i] = -1;
    if (i < NUM_RELS) ws[OFF_CUR + i] = 0;
}

// Kernel 2: last[dst] = max edge index with that dst
__global__ void edge_max_kernel(const int* __restrict__ edges, int* __restrict__ ws) {
    int e = blockIdx.x * blockDim.x + threadIdx.x;
    if (e < N_EDGES) {
        int dst = edges[e * 3 + 2];
        atomicMax(&ws[OFF_LAST + dst], e);
    }
}

// Kernel 3: bucket nodes by rel of their last incoming edge
__global__ void bucket_kernel(const int* __restrict__ edges, int* __restrict__ ws) {
    int n = blockIdx.x * blockDim.x + threadIdx.x;
    if (n >= N_NODES) return;
    int li = ws[OFF_LAST + n];
    if (li < 0) return;
    int r = edges[li * 3 + 1];
    int s = edges[li * 3 + 0];
    int pos = atomicAdd(&ws[OFF_CUR + r], 1);
    if (pos < CAP) {
        ws[OFF_BN + r * CAP + pos] = n;
        ws[OFF_BS + r * CAP + pos] = s;
    }
}

// Kernel 4: out = h @ wself  (dense, all nodes). wself staged in LDS per block.
__global__ __launch_bounds__(256) void self_kernel(const float* __restrict__ h,
                                                   const float* __restrict__ wself,
                                                   float* __restrict__ out) {
    __shared__ float W[DIM * DIM];
    {
        const float4* w4 = (const float4*)wself;
        float4* l4 = (float4*)W;
        int t = threadIdx.x;
#pragma unroll
        for (int k = 0; k < 4; ++k) l4[t + k * 256] = w4[t + k * 256];
    }
    __syncthreads();

    int wave = threadIdx.x >> 6;
    int lane = threadIdx.x & 63;
    int base = blockIdx.x * NB + wave * (NB / 4);  // 8 nodes per wave

    for (int j = 0; j < NB / 4; j += 2) {
        int n0 = base + j, n1 = base + j + 1;
        bool v0 = n0 < N_NODES, v1 = n1 < N_NODES;
        float a0 = v0 ? h[n0 * DIM + lane] : 0.f;
        float a1 = v1 ? h[n1 * DIM + lane] : 0.f;
        float acc0 = 0.f, acc1 = 0.f;
#pragma unroll
        for (int i = 0; i < DIM; ++i) {
            float w = W[i * DIM + lane];          // bank o%32, 2-way = free
            acc0 = fmaf(__shfl(a0, i), w, acc0);
            acc1 = fmaf(__shfl(a1, i), w, acc1);
        }
        if (v0) out[n0 * DIM + lane] = acc0;
        if (v1) out[n1 * DIM + lane] = acc1;
    }
}

// Kernel 5: out[n] += h[src] @ weight[rel] for bucketed nodes.
// grid = NUM_RELS * TILES_PER_REL blocks; block -> (rel, tile).
__global__ __launch_bounds__(256) void msg_kernel(const float* __restrict__ h,
                                                  const float* __restrict__ weight,
                                                  const int* __restrict__ ws,
                                                  float* __restrict__ out) {
    int rel  = blockIdx.x >> 4;       // / TILES_PER_REL
    int tile = blockIdx.x & 15;
    int c = ws[OFF_CUR + rel];
    if (c > CAP) c = CAP;
    int start = tile * NB;
    if (start >= c) return;

    __shared__ float W[DIM * DIM];
    {
        const float4* w4 = (const float4*)(weight + (long)rel * DIM * DIM);
        float4* l4 = (float4*)W;
        int t = threadIdx.x;
#pragma unroll
        for (int k = 0; k < 4; ++k) l4[t + k * 256] = w4[t + k * 256];
    }
    __syncthreads();

    int wave = threadIdx.x >> 6;
    int lane = threadIdx.x & 63;
    int base = start + wave * (NB / 4);
    const int* bn = ws + OFF_BN + rel * CAP;
    const int* bs = ws + OFF_BS + rel * CAP;

    for (int j = 0; j < NB / 4; j += 2) {
        int i0 = base + j, i1 = base + j + 1;
        bool v0 = i0 < c, v1 = i1 < c;        // wave-uniform
        int n0 = v0 ? bn[i0] : 0, s0 = v0 ? bs[i0] : 0;
        int n1 = v1 ? bn[i1] : 0, s1 = v1 ? bs[i1] : 0;
        float a0 = v0 ? h[s0 * DIM + lane] : 0.f;
        float a1 = v1 ? h[s1 * DIM + lane] : 0.f;
        float acc0 = 0.f, acc1 = 0.f;
#pragma unroll
        for (int i = 0; i < DIM; ++i) {
            float w = W[i * DIM + lane];
            acc0 = fmaf(__shfl(a0, i), w, acc0);
            acc1 = fmaf(__shfl(a1, i), w, acc1);
        }
        if (v0) out[n0 * DIM + lane] += acc0;
        if (v1) out[n1 * DIM + lane] += acc1;
    }
}

extern "C" void kernel_launch(void* const* d_in, const int* in_sizes, int n_in,
                              void* d_out, int out_size, void* d_ws, size_t ws_size,
                              hipStream_t stream) {
    const float* h      = (const float*)d_in[0];
    const int*   edges  = (const int*)d_in[1];
    const float* weight = (const float*)d_in[2];
    const float* wself  = (const float*)d_in[3];
    float* out = (float*)d_out;
    int* ws = (int*)d_ws;

    init_kernel<<<(N_NODES + 255) / 256, 256, 0, stream>>>(ws);
    edge_max_kernel<<<(N_EDGES + 255) / 256, 256, 0, stream>>>(edges, ws);
    bucket_kernel<<<(N_NODES + 255) / 256, 256, 0, stream>>>(edges, ws);
    self_kernel<<<(N_NODES + NB - 1) / NB, 256, 0, stream>>>(h, wself, out);
    msg_kernel<<<NUM_RELS * TILES_PER_REL, 256, 0, stream>>>(h, weight, ws, out);
}

// Round 3
// 104.159 us; speedup vs baseline: 2.4038x; 2.4038x over previous
//
#include <hip/hip_runtime.h>

#define N_NODES 50000
#define N_EDGES 100000
#define NUM_RELS 200
#define DIM 64
#define CAP 512
#define TILES 8   // CAP/64 waves per rel

// ---- workspace layout (int32 elements) ----
#define OFF_LAST 0
#define OFF_CUR  50000
#define OFF_BN   50200
#define OFF_BS   (50200 + NUM_RELS * CAP)

__global__ void init_kernel(int* __restrict__ ws) {
    int i = blockIdx.x * 256 + threadIdx.x;
    if (i < N_NODES) ws[OFF_LAST + i] = -1;
    if (i < NUM_RELS) ws[OFF_CUR + i] = 0;
}

__global__ void edge_max_kernel(const int* __restrict__ edges, int* __restrict__ ws) {
    int e = blockIdx.x * 256 + threadIdx.x;
    if (e < N_EDGES) atomicMax(&ws[OFF_LAST + edges[e * 3 + 2]], e);
}

__global__ void bucket_kernel(const int* __restrict__ edges, int* __restrict__ ws) {
    int n = blockIdx.x * 256 + threadIdx.x;
    if (n >= N_NODES) return;
    int li = ws[OFF_LAST + n];
    if (li < 0) return;
    int r = edges[li * 3 + 1];
    int s = edges[li * 3 + 0];
    int pos = atomicAdd(&ws[OFF_CUR + r], 1);
    if (pos < CAP) {
        ws[OFF_BN + r * CAP + pos] = n;
        ws[OFF_BS + r * CAP + pos] = s;
    }
}

// 8-row FMA block: h chunk (8 per-lane floats) x W rows (wave-uniform -> SGPR)
__device__ __forceinline__ void body8(float acc[DIM], const float* __restrict__ Wr,
                                      float4 ha, float4 hb) {
    float hv[8] = {ha.x, ha.y, ha.z, ha.w, hb.x, hb.y, hb.z, hb.w};
#pragma unroll
    for (int i = 0; i < 8; ++i) {
#pragma unroll
        for (int o = 0; o < DIM; ++o)
            acc[o] = fmaf(hv[i], Wr[i * DIM + o], acc[o]);
    }
}

// out[n] = h[n] @ wself   (lane = node; wself rows scalar-loaded)
__global__ __launch_bounds__(64) void self_kernel(const float* __restrict__ h,
                                                  const float* __restrict__ wself,
                                                  float* __restrict__ out) {
    int n = blockIdx.x * 64 + threadIdx.x;
    bool valid = n < N_NODES;
    int nc = valid ? n : (N_NODES - 1);
    const float* hp = h + (size_t)nc * DIM;

    float acc[DIM];
#pragma unroll
    for (int o = 0; o < DIM; ++o) acc[o] = 0.f;

    float4 ha = *(const float4*)(hp);
    float4 hb = *(const float4*)(hp + 4);
    for (int ib = 0; ib < DIM - 8; ib += 8) {   // rolled; prefetch next h chunk
        float4 na = *(const float4*)(hp + ib + 8);
        float4 nb = *(const float4*)(hp + ib + 12);
        body8(acc, wself + ib * DIM, ha, hb);
        ha = na; hb = nb;
    }
    body8(acc, wself + (DIM - 8) * DIM, ha, hb);

    if (valid) {
        float* op = out + (size_t)n * DIM;
#pragma unroll
        for (int o = 0; o < DIM; o += 4)
            *(float4*)(op + o) = make_float4(acc[o], acc[o + 1], acc[o + 2], acc[o + 3]);
    }
}

// out[n] += h[src] @ weight[rel]  (lane = bucket entry; one wave per 64 entries)
__global__ __launch_bounds__(64) void msg_kernel(const float* __restrict__ h,
                                                 const float* __restrict__ weight,
                                                 const int* __restrict__ ws,
                                                 float* __restrict__ out) {
    int rel  = blockIdx.x >> 3;     // / TILES
    int tile = blockIdx.x & 7;
    int c = ws[OFF_CUR + rel];
    if (c > CAP) c = CAP;
    int start = tile * 64;
    if (start >= c) return;

    int lane = threadIdx.x;
    int pos = start + lane;
    bool valid = pos < c;
    int cp = valid ? pos : (c - 1);
    int n = ws[OFF_BN + rel * CAP + cp];
    int s = ws[OFF_BS + rel * CAP + cp];
    const float* hp = h + (size_t)s * DIM;
    const float* W  = weight + (size_t)rel * DIM * DIM;

    float acc[DIM];
#pragma unroll
    for (int o = 0; o < DIM; ++o) acc[o] = 0.f;

    float4 ha = *(const float4*)(hp);
    float4 hb = *(const float4*)(hp + 4);
    for (int ib = 0; ib < DIM - 8; ib += 8) {
        float4 na = *(const float4*)(hp + ib + 8);
        float4 nb = *(const float4*)(hp + ib + 12);
        body8(acc, W + ib * DIM, ha, hb);
        ha = na; hb = nb;
    }
    body8(acc, W + (DIM - 8) * DIM, ha, hb);

    if (valid) {
        float* op = out + (size_t)n * DIM;
#pragma unroll
        for (int o = 0; o < DIM; o += 4) {
            float4 cur = *(const float4*)(op + o);
            *(float4*)(op + o) = make_float4(cur.x + acc[o], cur.y + acc[o + 1],
                                             cur.z + acc[o + 2], cur.w + acc[o + 3]);
        }
    }
}

extern "C" void kernel_launch(void* const* d_in, const int* in_sizes, int n_in,
                              void* d_out, int out_size, void* d_ws, size_t ws_size,
                              hipStream_t stream) {
    const float* h      = (const float*)d_in[0];
    const int*   edges  = (const int*)d_in[1];
    const float* weight = (const float*)d_in[2];
    const float* wself  = (const float*)d_in[3];
    float* out = (float*)d_out;
    int* ws = (int*)d_ws;

    init_kernel<<<(N_NODES + 255) / 256, 256, 0, stream>>>(ws);
    edge_max_kernel<<<(N_EDGES + 255) / 256, 256, 0, stream>>>(edges, ws);
    bucket_kernel<<<(N_NODES + 255) / 256, 256, 0, stream>>>(edges, ws);
    self_kernel<<<(N_NODES + 63) / 64, 64, 0, stream>>>(h, wself, out);
    msg_kernel<<<NUM_RELS * TILES, 64, 0, stream>>>(h, weight, ws, out);
}